// Round 5
// baseline (241.670 us; speedup 1.0000x reference)
//
#include <hip/hip_runtime.h>
#include <cmath>

namespace {
constexpr int BN = 1024;
constexpr int NC = 96;
constexpr int MT = 256;
constexpr int UL = 40;
constexpr int LS = 81;     // 2*UL+1 states
constexpr int PAIRS = 41;  // pairs per row (lane i -> states 2i, 2i+1)

template <int CTRL>
__device__ __forceinline__ float dppf(float v) {
  return __builtin_bit_cast(
      float, __builtin_amdgcn_update_dpp(0, __builtin_bit_cast(int, v), CTRL,
                                         0xf, 0xf, true));
}
__device__ __forceinline__ float rl63(float x) {
  return __builtin_bit_cast(
      float, __builtin_amdgcn_readlane(__builtin_bit_cast(int, x), 63));
}
__device__ __forceinline__ float wave_sum(float x) {
  x += dppf<0x111>(x);
  x += dppf<0x112>(x);
  x += dppf<0x114>(x);
  x += dppf<0x118>(x);
  x += dppf<0x142>(x);
  x += dppf<0x143>(x);
  return rl63(x);
}
// lane i <- lane i-1 (lane 0 <- 0)
__device__ __forceinline__ float wave_shr1(float v) { return dppf<0x138>(v); }
__device__ __forceinline__ float fast_rcp(float x) {
  return __builtin_amdgcn_rcpf(x);
}
__device__ __forceinline__ unsigned packu(float a, float b) {
  unsigned ua = __builtin_bit_cast(unsigned, a) >> 16;
  unsigned ub = __builtin_bit_cast(unsigned, b) & 0xffff0000u;
  return ua | ub;
}
__device__ __forceinline__ float bf_lo(unsigned u) {
  return __builtin_bit_cast(float, u << 16);
}
__device__ __forceinline__ float bf_hi(unsigned u) {
  return __builtin_bit_cast(float, u & 0xffff0000u);
}

constexpr float FQ = 1e8f;      // block-start row scale
constexpr float SEPS = 1e-30f;  // rcp-input floor (NaN-proof)

// One wave per (item, phase). Lane i owns states s=2i, 2i+1.
// DEFERRED-SUM scheme (verified round 3) + DEPTH-4 REGISTER-ROTATED PREFETCH
// (round 4) — NOW PINNED: sched_barrier(0) brackets every reload cluster so
// the MachineScheduler cannot sink the loads toward their uses (round 4's
// VGPR=72 proved it had collapsed the pipeline to ~depth-1). With the loads
// pinned ~3.3 block-walls ahead of their s_waitcnt, the 41-row pL gather
// latency is hidden. All math bit-identical to the verified round-3 scheme.
// Outputs TRANSPOSED [pair][t] (bf16x2); combine fused with final reduce.
__global__ __launch_bounds__(64) void chain_kernel(
    const float* __restrict__ gout, const int* __restrict__ glabel,
    const int* __restrict__ gw, unsigned* __restrict__ xa,
    unsigned* __restrict__ xb, unsigned* __restrict__ counter) {
  const int bx = blockIdx.x;
  const int b = bx >> 1, ph = bx & 1;
  const int i = threadIdx.x;
  if (bx == 0 && i == 0) *counter = 0u;  // reset for combine's finish-flag
  const float* P = gout + (size_t)b * (NC * MT);  // P[c*MT + t]
  const int* lab = glabel + b * UL;
  const int T = gw[b] >> 2;  // [128,256]

  const int s0 = 2 * i, s1 = s0 + 1;
  const float h0f = (i <= 40) ? 1.f : 0.f;
  const float h1f = (i <= 39) ? 1.f : 0.f;
  const int iw = (i <= 40) ? i : 40;
  const bool act = (i <= 40);

  const float* pB;
  const float* pL;
  float mskf;
  unsigned* outp;
  if (ph == 0) {  // alpha
    const int li = (i < UL) ? lab[i] : 0;
    const int lm = (i >= 1 && i < UL) ? lab[i - 1] : 0;
    pB = P;
    pL = P + (size_t)li * MT;
    mskf = (i >= 1 && i <= 39 && li != lm) ? 1.f : 0.f;
    outp = xa + ((size_t)b * PAIRS + iw) * MT;
  } else {  // beta: class-flipped probs, reversed labels
    const int rli = (i < UL) ? lab[UL - 1 - i] : 0;
    const int rlm = (i >= 1 && i < UL) ? lab[UL - i] : 0;
    pB = P + (size_t)(NC - 1) * MT;
    pL = P + (size_t)(NC - 1 - rli) * MT;
    mskf = (i >= 1 && i <= 39 && rli != rlm) ? 1.f : 0.f;
    outp = xb + ((size_t)b * PAIRS + (40 - iw)) * MT;  // pair-reversed column
  }

  // ---- depth-4 prefetch pipeline: issue blocks 0..3 up front ----
  float4 q0a = *(const float4*)(pB + 0),  q0b = *(const float4*)(pB + 4);
  float4 r0a = *(const float4*)(pL + 0),  r0b = *(const float4*)(pL + 4);
  float4 q1a = *(const float4*)(pB + 8),  q1b = *(const float4*)(pB + 12);
  float4 r1a = *(const float4*)(pL + 8),  r1b = *(const float4*)(pL + 12);
  float4 q2a = *(const float4*)(pB + 16), q2b = *(const float4*)(pB + 20);
  float4 r2a = *(const float4*)(pL + 16), r2b = *(const float4*)(pL + 20);
  float4 q3a = *(const float4*)(pB + 24), q3b = *(const float4*)(pB + 28);
  float4 r3a = *(const float4*)(pL + 24), r3b = *(const float4*)(pL + 28);
  __builtin_amdgcn_sched_barrier(0);  // pin prologue loads above this point

  // ---- t = 0 ----
  float v0 = (i == 0) ? q0a.x : 0.f;
  float v1 = (i == 0) ? r0a.x : 0.f;

  float f0[8], f1[8], sv[8];  // 8-step row buffer + per-lane row totals
  if (ph == 0) {
    sv[0] = v0 + v1;               // raw scale matches x=1 convention
    f0[0] = (i == 0) ? 1.f : 0.f;  // x = a_raw/p at t=0
    f1[0] = f0[0];
    v0 *= FQ;
    v1 *= FQ;
  } else {
    v0 *= FQ;
    v1 *= FQ;
    sv[0] = v0 + v1;
    f0[0] = v0;
    f1[0] = 0.f;  // overwritten by step k=1's pm1 (same scale)
  }

#define CTC_STEP(T_, K_, PBV, PLV, DOMASK)                            \
  {                                                                   \
    float pm1 = wave_shr1(v1);                                        \
    if (ph == 1 && (K_) >= 1) f1[(K_)-1] = pm1;                       \
    float u0 = v0 + pm1;                                              \
    float u1 = (v0 + v1) + pm1 * mskf;                                \
    if (DOMASK) {                                                     \
      const int start_ = LS - 2 * (T - (T_));                         \
      if (s0 < start_) u0 = 0.f;                                      \
      if (s1 < start_) u1 = 0.f;                                      \
    }                                                                 \
    const float x0 = u0 * h0f, x1 = u1 * h1f;                         \
    float n0 = x0 * (PBV);                                            \
    float n1 = x1 * (PLV);                                            \
    sv[(K_)] = n0 + n1;                                               \
    v0 = n0; v1 = n1;                                                 \
    if (ph == 0) { f0[(K_)] = x0; f1[(K_)] = x1; }                    \
    else { f0[(K_)] = n0; }                                           \
  }

  // 8 independent wave-sums, breadth-first: 8-way ILP on the DPP trees.
#define WS_LEVEL(CTRL)                                                \
  {                                                                   \
    _Pragma("unroll")                                                 \
    for (int k = 0; k < 8; ++k) sv[k] += dppf<CTRL>(sv[k]);           \
  }

#define CTC_BURST(T0_)                                                \
  {                                                                   \
    if (ph == 1) f1[7] = wave_shr1(v1); /* before rescale! */         \
    WS_LEVEL(0x111) WS_LEVEL(0x112) WS_LEVEL(0x114)                   \
    WS_LEVEL(0x118) WS_LEVEL(0x142) WS_LEVEL(0x143)                   \
    _Pragma("unroll")                                                 \
    for (int k = 0; k < 8; ++k) sv[k] = rl63(sv[k]);                  \
    if (act) {                                                        \
      unsigned ob[8];                                                 \
      _Pragma("unroll")                                               \
      for (int k = 0; k < 8; ++k) {                                   \
        float inv = fast_rcp(fmaxf(sv[k], SEPS));                     \
        ob[k] = packu(f0[k] * inv, f1[k] * inv);                      \
      }                                                               \
      if ((T0_) + 7 < T) {                                            \
        *reinterpret_cast<uint4*>(outp + (T0_)) =                     \
            make_uint4(ob[0], ob[1], ob[2], ob[3]);                   \
        *reinterpret_cast<uint4*>(outp + (T0_) + 4) =                 \
            make_uint4(ob[4], ob[5], ob[6], ob[7]);                   \
      } else {                                                        \
        _Pragma("unroll")                                             \
        for (int k = 0; k < 8; ++k)                                   \
          if ((T0_) + k < T) outp[(T0_) + k] = ob[k];                 \
      }                                                               \
    }                                                                 \
    float rb = FQ * fast_rcp(fmaxf(sv[7], SEPS));                     \
    rb = fminf(fmaxf(rb, 1e-20f), 1e20f);                             \
    v0 *= rb; v1 *= rb;                                               \
  }

  // One 8-step block using buffer (QA,QB,RA,RB); re-issues that buffer's
  // loads for T0_+32 after the last use. The sched_barrier(0) pair PINS the
  // reload cluster here — the scheduler may not sink it toward its use
  // (3+ blocks later), so the loads stay ~3.3 block-walls in flight.
#define CTC_BLOCK(T0_, QA, QB, RA, RB, DOMASK)                        \
  {                                                                   \
    CTC_STEP((T0_) + 0, 0, QA.x, RA.x, DOMASK)                        \
    CTC_STEP((T0_) + 1, 1, QA.y, RA.y, DOMASK)                        \
    CTC_STEP((T0_) + 2, 2, QA.z, RA.z, DOMASK)                        \
    CTC_STEP((T0_) + 3, 3, QA.w, RA.w, DOMASK)                        \
    CTC_STEP((T0_) + 4, 4, QB.x, RB.x, DOMASK)                        \
    CTC_STEP((T0_) + 5, 5, QB.y, RB.y, DOMASK)                        \
    CTC_STEP((T0_) + 6, 6, QB.z, RB.z, DOMASK)                        \
    CTC_STEP((T0_) + 7, 7, QB.w, RB.w, DOMASK)                        \
    __builtin_amdgcn_sched_barrier(0);                                \
    {                                                                 \
      int np = (T0_) + 32;                                            \
      if (np > 248) np = 248;                                         \
      QA = *(const float4*)(pB + np);                                 \
      QB = *(const float4*)(pB + np + 4);                             \
      RA = *(const float4*)(pL + np);                                 \
      RB = *(const float4*)(pL + np + 4);                             \
    }                                                                 \
    __builtin_amdgcn_sched_barrier(0);                                \
    CTC_BURST(T0_)                                                    \
  }

  // ---- prologue block 0: steps 1..7 (T>=128 -> unmasked), uses buf0 ----
  CTC_STEP(1, 1, q0a.y, r0a.y, false)
  CTC_STEP(2, 2, q0a.z, r0a.z, false)
  CTC_STEP(3, 3, q0a.w, r0a.w, false)
  CTC_STEP(4, 4, q0b.x, r0b.x, false)
  CTC_STEP(5, 5, q0b.y, r0b.y, false)
  CTC_STEP(6, 6, q0b.z, r0b.z, false)
  CTC_STEP(7, 7, q0b.w, r0b.w, false)
  __builtin_amdgcn_sched_barrier(0);
  {
    q0a = *(const float4*)(pB + 32); q0b = *(const float4*)(pB + 36);
    r0a = *(const float4*)(pL + 32); r0b = *(const float4*)(pL + 36);
  }
  __builtin_amdgcn_sched_barrier(0);
  CTC_BURST(0)

  // ---- main: groups of 4 blocks, unmasked (last step t0+31 <= T-41) ----
  int t0 = 8;
  for (; t0 + 72 <= T; t0 += 32) {
    CTC_BLOCK(t0,      q1a, q1b, r1a, r1b, false)
    CTC_BLOCK(t0 + 8,  q2a, q2b, r2a, r2b, false)
    CTC_BLOCK(t0 + 16, q3a, q3b, r3a, r3b, false)
    CTC_BLOCK(t0 + 24, q0a, q0b, r0a, r0b, false)
  }
  // ---- tail: masked blocks (wave-uniform guards keep rotation static) ----
  for (; t0 < T; t0 += 32) {
    CTC_BLOCK(t0, q1a, q1b, r1a, r1b, true)
    if (t0 + 8 < T)  { CTC_BLOCK(t0 + 8,  q2a, q2b, r2a, r2b, true) }
    if (t0 + 16 < T) { CTC_BLOCK(t0 + 16, q3a, q3b, r3a, r3b, true) }
    if (t0 + 24 < T) { CTC_BLOCK(t0 + 24, q0a, q0b, r0a, r0b, true) }
  }
#undef CTC_STEP
#undef CTC_BURST
#undef CTC_BLOCK
#undef WS_LEVEL
}

// Fully parallel combine: block = item, thread = t. All loads coalesced
// (transposed layout). lh_t = sum_p x'[p][t] * b'[p][T-1-t]; rows are
// pre-normalized at store so no sums arrays are needed.
// Final reduce FUSED via last-block-done pattern (device-scope atomic +
// fences; counter reset by chain_kernel, ordered by the kernel boundary).
__global__ __launch_bounds__(256) void combine_kernel(
    const int* __restrict__ gw, const unsigned* __restrict__ xa,
    const unsigned* __restrict__ xb, float* __restrict__ loss_out,
    unsigned* __restrict__ counter, float* __restrict__ out) {
  __shared__ float part[4];
  __shared__ double sm[256];
  __shared__ int lastb;
  const int b = blockIdx.x;
  const int tid = threadIdx.x;
  const int T = gw[b] >> 2;
  float lsum = 0.f;
  if (tid < T) {
    const unsigned* A = xa + (size_t)b * PAIRS * MT + tid;
    const unsigned* Bb = xb + (size_t)b * PAIRS * MT + (T - 1 - tid);
    float d = 0.f;
#pragma unroll
    for (int p = 0; p < PAIRS; ++p) {
      const unsigned av = A[p * MT];
      const unsigned bv = Bb[p * MT];
      d = fmaf(bf_lo(av), bf_lo(bv), d);
      d = fmaf(bf_hi(av), bf_hi(bv), d);
    }
    lsum = -__logf(fmaxf(d, 1e-37f));
  }
  lsum = wave_sum(lsum);
  if ((tid & 63) == 0) part[tid >> 6] = lsum;
  __syncthreads();
  if (tid == 0) {
    float L = part[0] + part[1] + part[2] + part[3];
    loss_out[b] = fminf(fmaxf(L, -1e30f), 1e30f);  // fmin/fmax absorb NaN
    __threadfence();  // release own loss before signalling
    lastb = (atomicAdd(counter, 1u) == (unsigned)(BN - 1)) ? 1 : 0;
  }
  __syncthreads();
  if (lastb) {  // last block: all losses visible -> deterministic final sum
    __threadfence();  // acquire
    double s = 0.0;
    for (int k = tid; k < BN; k += 256) s += (double)loss_out[k];
    sm[tid] = s;
    __syncthreads();
    for (int w = 128; w >= 1; w >>= 1) {
      if (tid < w) sm[tid] += sm[tid + w];
      __syncthreads();
    }
    if (tid == 0) out[0] = (float)sm[0];
  }
}
}  // namespace

extern "C" void kernel_launch(void* const* d_in, const int* in_sizes, int n_in,
                              void* d_out, int out_size, void* d_ws, size_t ws_size,
                              hipStream_t stream) {
  const float* gout = (const float*)d_in[0];
  const int* glabel = (const int*)d_in[1];
  const int* gw = (const int*)d_in[2];
  unsigned* xa = (unsigned*)d_ws;                  // BN*PAIRS*MT uints (43 MB)
  unsigned* xb = xa + (size_t)BN * PAIRS * MT;     // 43 MB
  float* loss = (float*)(xb + (size_t)BN * PAIRS * MT);  // 4 KB
  unsigned* counter = (unsigned*)(loss + BN);            // 4 B
  chain_kernel<<<2 * BN, 64, 0, stream>>>(gout, glabel, gw, xa, xb, counter);
  combine_kernel<<<BN, 256, 0, stream>>>(gw, xa, xb, loss, counter,
                                         (float*)d_out);
}

// Round 7
// 190.636 us; speedup vs baseline: 1.2677x; 1.2677x over previous
//
#include <hip/hip_runtime.h>
#include <cmath>

namespace {
constexpr int BN = 1024;
constexpr int NC = 96;
constexpr int MT = 256;
constexpr int UL = 40;
constexpr int LS = 81;     // 2*UL+1 states
constexpr int PAIRS = 41;  // pairs per row (lane i -> states 2i, 2i+1)

template <int CTRL>
__device__ __forceinline__ float dppf(float v) {
  return __builtin_bit_cast(
      float, __builtin_amdgcn_update_dpp(0, __builtin_bit_cast(int, v), CTRL,
                                         0xf, 0xf, true));
}
__device__ __forceinline__ float rl63(float x) {
  return __builtin_bit_cast(
      float, __builtin_amdgcn_readlane(__builtin_bit_cast(int, x), 63));
}
__device__ __forceinline__ float wave_sum(float x) {
  x += dppf<0x111>(x);
  x += dppf<0x112>(x);
  x += dppf<0x114>(x);
  x += dppf<0x118>(x);
  x += dppf<0x142>(x);
  x += dppf<0x143>(x);
  return rl63(x);
}
// lane i <- lane i-1 (lane 0 <- 0)
__device__ __forceinline__ float wave_shr1(float v) { return dppf<0x138>(v); }
__device__ __forceinline__ float fast_rcp(float x) {
  return __builtin_amdgcn_rcpf(x);
}
__device__ __forceinline__ unsigned packu(float a, float b) {
  unsigned ua = __builtin_bit_cast(unsigned, a) >> 16;
  unsigned ub = __builtin_bit_cast(unsigned, b) & 0xffff0000u;
  return ua | ub;
}
__device__ __forceinline__ float bf_lo(unsigned u) {
  return __builtin_bit_cast(float, u << 16);
}
__device__ __forceinline__ float bf_hi(unsigned u) {
  return __builtin_bit_cast(float, u & 0xffff0000u);
}

constexpr float FQ = 1e8f;      // block-start row scale
constexpr float SEPS = 1e-30f;  // rcp-input floor (NaN-proof)

// One wave per (item, phase). Lane i owns states s=2i, 2i+1.
// DEFERRED-SUM scheme (verified round 3): inner 8-step loop carries no
// wave_sum/rcp; per-lane row totals go to sv[k]; block-end does 8 independent
// breadth-first DPP sums, normalizes rows by their own raw sum at pack time,
// and rescales v once per block to sum FQ.
// NEW (round 7): COALESCED STORE LAYOUT [b][t][pair]. Lane i stores ob[k] to
// row t0+k, column i — each of the 8 dword stores is wave-coalesced into ~3
// cache lines (vs 41 lines/store with the old [pair][t] layout). Theory: the
// invariant ~5500cyc/block wall is the compiler's s_waitcnt before reusing
// the store-data regs (ob[]), i.e. the fragmented stores' ack latency under
// 2048-wave write-queue congestion. Coalescing shrinks line-transactions
// 82 -> 24 per block. Combine reads become per-thread contiguous as a bonus.
__global__ __launch_bounds__(64) void chain_kernel(
    const float* __restrict__ gout, const int* __restrict__ glabel,
    const int* __restrict__ gw, unsigned* __restrict__ xa,
    unsigned* __restrict__ xb) {
  const int bx = blockIdx.x;
  const int b = bx >> 1, ph = bx & 1;
  const int i = threadIdx.x;
  const float* P = gout + (size_t)b * (NC * MT);  // P[c*MT + t]
  const int* lab = glabel + b * UL;
  const int T = gw[b] >> 2;  // [128,256]

  const int s0 = 2 * i, s1 = s0 + 1;
  const float h0f = (i <= 40) ? 1.f : 0.f;
  const float h1f = (i <= 39) ? 1.f : 0.f;
  const int iw = (i <= 40) ? i : 40;
  const bool act = (i <= 40);

  const float* pB;
  const float* pL;
  float mskf;
  unsigned* outp;  // points at [b][0][col] in the [b][t][pair] layout
  if (ph == 0) {  // alpha
    const int li = (i < UL) ? lab[i] : 0;
    const int lm = (i >= 1 && i < UL) ? lab[i - 1] : 0;
    pB = P;
    pL = P + (size_t)li * MT;
    mskf = (i >= 1 && i <= 39 && li != lm) ? 1.f : 0.f;
    outp = xa + (size_t)b * MT * PAIRS + iw;
  } else {  // beta: class-flipped probs, reversed labels
    const int rli = (i < UL) ? lab[UL - 1 - i] : 0;
    const int rlm = (i >= 1 && i < UL) ? lab[UL - i] : 0;
    pB = P + (size_t)(NC - 1) * MT;
    pL = P + (size_t)(NC - 1 - rli) * MT;
    mskf = (i >= 1 && i <= 39 && rli != rlm) ? 1.f : 0.f;
    outp = xb + (size_t)b * MT * PAIRS + (40 - iw);  // pair-reversed column
  }

  // ---- prob pipeline: current block unpacked, next block in flight ----
  float pbv[8], plv[8];
  float4 LA = *(const float4*)(pB + 0), LB = *(const float4*)(pB + 4);
  float4 MA = *(const float4*)(pL + 0), MB = *(const float4*)(pL + 4);
  pbv[0] = LA.x; pbv[1] = LA.y; pbv[2] = LA.z; pbv[3] = LA.w;
  pbv[4] = LB.x; pbv[5] = LB.y; pbv[6] = LB.z; pbv[7] = LB.w;
  plv[0] = MA.x; plv[1] = MA.y; plv[2] = MA.z; plv[3] = MA.w;
  plv[4] = MB.x; plv[5] = MB.y; plv[6] = MB.z; plv[7] = MB.w;
  LA = *(const float4*)(pB + 8); LB = *(const float4*)(pB + 12);
  MA = *(const float4*)(pL + 8); MB = *(const float4*)(pL + 12);

  // ---- t = 0 ----
  float v0 = (i == 0) ? pbv[0] : 0.f;
  float v1 = (i == 0) ? plv[0] : 0.f;

  float f0[8], f1[8], sv[8];  // 8-step row buffer + per-lane row totals
  if (ph == 0) {
    sv[0] = v0 + v1;               // raw scale matches x=1 convention
    f0[0] = (i == 0) ? 1.f : 0.f;  // x = a_raw/p at t=0
    f1[0] = f0[0];
    v0 *= FQ;
    v1 *= FQ;
  } else {
    v0 *= FQ;
    v1 *= FQ;
    sv[0] = v0 + v1;
    f0[0] = v0;
    f1[0] = 0.f;  // overwritten by step k=1's pm1 (same scale)
  }

#define CTC_STEP(T_, K_, DOMASK)                                      \
  {                                                                   \
    float pm1 = wave_shr1(v1);                                        \
    if (ph == 1 && (K_) >= 1) f1[(K_)-1] = pm1;                       \
    float u0 = v0 + pm1;                                              \
    float u1 = (v0 + v1) + pm1 * mskf;                                \
    if (DOMASK) {                                                     \
      const int start_ = LS - 2 * (T - (T_));                         \
      if (s0 < start_) u0 = 0.f;                                      \
      if (s1 < start_) u1 = 0.f;                                      \
    }                                                                 \
    const float x0 = u0 * h0f, x1 = u1 * h1f;                         \
    float n0 = x0 * pbv[(K_)];                                        \
    float n1 = x1 * plv[(K_)];                                        \
    sv[(K_)] = n0 + n1;                                               \
    v0 = n0; v1 = n1;                                                 \
    if (ph == 0) { f0[(K_)] = x0; f1[(K_)] = x1; }                    \
    else { f0[(K_)] = n0; }                                           \
  }

  // 8 independent wave-sums, breadth-first: 8-way ILP on the DPP trees.
#define WS_LEVEL(CTRL)                                                \
  {                                                                   \
    _Pragma("unroll")                                                 \
    for (int k = 0; k < 8; ++k) sv[k] += dppf<CTRL>(sv[k]);           \
  }

#define CTC_BURST(T0_)                                                \
  {                                                                   \
    if (ph == 1) f1[7] = wave_shr1(v1); /* before rescale! */         \
    WS_LEVEL(0x111) WS_LEVEL(0x112) WS_LEVEL(0x114)                   \
    WS_LEVEL(0x118) WS_LEVEL(0x142) WS_LEVEL(0x143)                   \
    _Pragma("unroll")                                                 \
    for (int k = 0; k < 8; ++k) sv[k] = rl63(sv[k]);                  \
    if (act) {                                                        \
      unsigned ob[8];                                                 \
      _Pragma("unroll")                                               \
      for (int k = 0; k < 8; ++k) {                                   \
        float inv = fast_rcp(fmaxf(sv[k], SEPS));                     \
        ob[k] = packu(f0[k] * inv, f1[k] * inv);                      \
      }                                                               \
      if ((T0_) + 7 < T) {                                            \
        _Pragma("unroll")                                             \
        for (int k = 0; k < 8; ++k)                                   \
          outp[((T0_) + k) * PAIRS] = ob[k];  /* wave-coalesced */    \
      } else {                                                        \
        _Pragma("unroll")                                             \
        for (int k = 0; k < 8; ++k)                                   \
          if ((T0_) + k < T) outp[((T0_) + k) * PAIRS] = ob[k];       \
      }                                                               \
    }                                                                 \
    float rb = FQ * fast_rcp(fmaxf(sv[7], SEPS));                     \
    rb = fminf(fmaxf(rb, 1e-20f), 1e20f);                             \
    v0 *= rb; v1 *= rb;                                               \
  }

#define CTC_UNPACK()                                                  \
  {                                                                   \
    pbv[0] = LA.x; pbv[1] = LA.y; pbv[2] = LA.z; pbv[3] = LA.w;       \
    pbv[4] = LB.x; pbv[5] = LB.y; pbv[6] = LB.z; pbv[7] = LB.w;       \
    plv[0] = MA.x; plv[1] = MA.y; plv[2] = MA.z; plv[3] = MA.w;       \
    plv[4] = MB.x; plv[5] = MB.y; plv[6] = MB.z; plv[7] = MB.w;       \
    int np = t0 + 8;                                                  \
    if (np > 248) np = 248;                                           \
    LA = *(const float4*)(pB + np); LB = *(const float4*)(pB + np + 4); \
    MA = *(const float4*)(pL + np); MB = *(const float4*)(pL + np + 4); \
  }

  // ---- prologue: steps 1..7, rows 0..7 (T>=128 -> unmasked) ----
#pragma unroll
  for (int k = 1; k < 8; ++k) CTC_STEP(k, k, false);
  CTC_BURST(0);

  // ---- main: unmasked fast path (t0+7 <= T-41 -> start_ <= 0) ----
  int t0 = 8;
  for (; t0 + 47 < T; t0 += 8) {
    CTC_UNPACK();
#pragma unroll
    for (int k = 0; k < 8; ++k) CTC_STEP(t0 + k, k, false);
    CTC_BURST(t0);
  }
  // ---- tail: masked blocks ----
  for (; t0 < T; t0 += 8) {
    CTC_UNPACK();
#pragma unroll
    for (int k = 0; k < 8; ++k) CTC_STEP(t0 + k, k, true);
    CTC_BURST(t0);
  }
#undef CTC_STEP
#undef CTC_BURST
#undef CTC_UNPACK
#undef WS_LEVEL
}

// Fully parallel combine: block = item, thread = t. With the [b][t][pair]
// layout each thread's two rows are CONTIGUOUS 41-dword runs (~3 lines each,
// vs 41 strided lines before). lh_t = sum_p x'[t][p] * b'[T-1-t][p]; rows
// are pre-normalized at store so no sums arrays are needed.
__global__ __launch_bounds__(256) void combine_kernel(
    const int* __restrict__ gw, const unsigned* __restrict__ xa,
    const unsigned* __restrict__ xb, float* __restrict__ loss_out) {
  const int b = blockIdx.x;
  const int tid = threadIdx.x;
  const int T = gw[b] >> 2;
  float lsum = 0.f;
  if (tid < T) {
    const unsigned* A = xa + ((size_t)b * MT + tid) * PAIRS;
    const unsigned* Bb = xb + ((size_t)b * MT + (T - 1 - tid)) * PAIRS;
    float d = 0.f;
#pragma unroll
    for (int p = 0; p < PAIRS; ++p) {
      const unsigned av = A[p];
      const unsigned bv = Bb[p];
      d = fmaf(bf_lo(av), bf_lo(bv), d);
      d = fmaf(bf_hi(av), bf_hi(bv), d);
    }
    lsum = -__logf(fmaxf(d, 1e-37f));
  }
  lsum = wave_sum(lsum);
  __shared__ float part[4];
  if ((tid & 63) == 0) part[tid >> 6] = lsum;
  __syncthreads();
  if (tid == 0) {
    float L = part[0] + part[1] + part[2] + part[3];
    loss_out[b] = fminf(fmaxf(L, -1e30f), 1e30f);  // fmin/fmax absorb NaN
  }
}

__global__ void reduce_kernel(const float* __restrict__ loss_in,
                              float* __restrict__ out) {
  __shared__ double sm[256];
  const int tid = threadIdx.x;
  double s = 0.0;
  for (int k = tid; k < BN; k += 256) s += (double)loss_in[k];
  sm[tid] = s;
  __syncthreads();
  for (int w = 128; w >= 1; w >>= 1) {
    if (tid < w) sm[tid] += sm[tid + w];
    __syncthreads();
  }
  if (tid == 0) out[0] = (float)sm[0];
}
}  // namespace

extern "C" void kernel_launch(void* const* d_in, const int* in_sizes, int n_in,
                              void* d_out, int out_size, void* d_ws, size_t ws_size,
                              hipStream_t stream) {
  const float* gout = (const float*)d_in[0];
  const int* glabel = (const int*)d_in[1];
  const int* gw = (const int*)d_in[2];
  unsigned* xa = (unsigned*)d_ws;                  // BN*MT*PAIRS uints (43 MB)
  unsigned* xb = xa + (size_t)BN * MT * PAIRS;     // 43 MB
  float* loss = (float*)(xb + (size_t)BN * MT * PAIRS);  // 4 KB
  chain_kernel<<<2 * BN, 64, 0, stream>>>(gout, glabel, gw, xa, xb);
  combine_kernel<<<BN, 256, 0, stream>>>(gw, xa, xb, loss);
  reduce_kernel<<<1, 256, 0, stream>>>(loss, (float*)d_out);
}